// Round 19
// baseline (1461.732 us; speedup 1.0000x reference)
//
#include <hip/hip_runtime.h>
#include <hip/hip_bf16.h>

typedef __hip_bfloat16 bf16;
typedef __attribute__((ext_vector_type(8))) short bf16x8;   // 8 bf16 = 4 VGPR
typedef __attribute__((ext_vector_type(4))) float f32x4;    // MFMA accumulator

__device__ __forceinline__ float b2f(bf16 v) { return __bfloat162float(v); }
__device__ __forceinline__ bf16 f2b(float v) { return __float2bfloat16(v); }
__device__ __forceinline__ unsigned short f2bb(float v) {   // RNE f32->bf16 bits
    unsigned int u = __float_as_uint(v);
    u += 0x7fffu + ((u >> 16) & 1u);
    return (unsigned short)(u >> 16);
}
// bf16x8 element k (compile-time k) -> f32 via bit shift
__device__ __forceinline__ float b2fx(bf16x8 v, int k) {
    return __uint_as_float(((unsigned int)(unsigned short)v[k]) << 16);
}

__device__ __forceinline__ f32x4 mfma16(bf16x8 a, bf16x8 b, f32x4 c) {
    return __builtin_amdgcn_mfma_f32_16x16x32_bf16(a, b, c, 0, 0, 0);
}

// Gather a B-fragment: rows k0..k0+7 of column col from row-major W[64][64] f32.
__device__ __forceinline__ bf16x8 load_bfrag(const float* __restrict__ W, int k0, int col) {
    bf16x8 f;
#pragma unroll
    for (int j = 0; j < 8; ++j)
        f[j] = (short)f2bb(W[(size_t)(k0 + j) * 64 + col]);
    return f;
}

// Swizzled byte offset for the HEAD restage tile ([64][64 bf16], 128B rows).
__device__ __forceinline__ int swzH(int row, int b) {
    return row * 128 + (b ^ ((row & 7) << 4));
}

// ======================= CSR build =======================
__device__ __forceinline__ void cr_one(int e,
        const int* __restrict__ dst_tw, int* __restrict__ deg_w,
        int* __restrict__ rank_tw, int ne_tw,
        const int* __restrict__ dst_wt, int* __restrict__ deg_tx,
        int* __restrict__ rank_wt, int ne_wt) {
    if (e < ne_tw) rank_tw[e] = atomicAdd(&deg_w[dst_tw[e]], 1);
    else {
        int e2 = e - ne_tw;
        if (e2 < ne_wt) rank_wt[e2] = atomicAdd(&deg_tx[dst_wt[e2]], 1);
    }
}
__global__ void count_rank2_kernel(const int* __restrict__ dst_tw, int* __restrict__ deg_w,
                                   int* __restrict__ rank_tw, int ne_tw,
                                   const int* __restrict__ dst_wt, int* __restrict__ deg_tx,
                                   int* __restrict__ rank_wt, int ne_wt) {
    int t = blockIdx.x * 256 + threadIdx.x;
    cr_one(t * 2 + 0, dst_tw, deg_w, rank_tw, ne_tw, dst_wt, deg_tx, rank_wt, ne_wt);
    cr_one(t * 2 + 1, dst_tw, deg_w, rank_tw, ne_tw, dst_wt, deg_tx, rank_wt, ne_wt);
}

// block-local exclusive scan over 1024 elems (256 thr x 4); writes block totals
__global__ void scan1m_kernel(const int* __restrict__ dw, int* __restrict__ ew,
                              int* __restrict__ pw, int nw, int npw,
                              const int* __restrict__ dt, int* __restrict__ et,
                              int* __restrict__ pt, int nt) {
    __shared__ int sT[256];
    const int* deg; int* excl; int* partial; int n; int b;
    if ((int)blockIdx.x < npw) { deg = dw; excl = ew; partial = pw; n = nw; b = blockIdx.x; }
    else { deg = dt; excl = et; partial = pt; n = nt; b = blockIdx.x - npw; }
    int tid = threadIdx.x;
    int base = b * 1024 + tid * 4;
    int v0 = (base + 0 < n) ? deg[base + 0] : 0;
    int v1 = (base + 1 < n) ? deg[base + 1] : 0;
    int v2 = (base + 2 < n) ? deg[base + 2] : 0;
    int v3 = (base + 3 < n) ? deg[base + 3] : 0;
    int t = v0 + v1 + v2 + v3;
    sT[tid] = t;
    __syncthreads();
    for (int off = 1; off < 256; off <<= 1) {   // Hillis-Steele inclusive
        int x = (tid >= off) ? sT[tid - off] : 0;
        __syncthreads();
        sT[tid] += x;
        __syncthreads();
    }
    int et2 = sT[tid] - t;
    if (tid == 255) partial[b] = sT[255];
    if (base + 0 < n) excl[base + 0] = et2;
    if (base + 1 < n) excl[base + 1] = et2 + v0;
    if (base + 2 < n) excl[base + 2] = et2 + v0 + v1;
    if (base + 3 < n) excl[base + 3] = et2 + v0 + v1 + v2;
}

// block 0 scans part_w, block 1 scans part_tx (each single-block full scan)
__global__ void scan2m_kernel(int* __restrict__ pw, int npw, int* __restrict__ pt, int npt) {
    __shared__ int sT[256];
    __shared__ int carry;
    int* partial = blockIdx.x ? pt : pw;
    int np = blockIdx.x ? npt : npw;
    int tid = threadIdx.x;
    if (tid == 0) carry = 0;
    __syncthreads();
    for (int c = 0; c < np; c += 256) {
        int i = c + tid;
        int v = (i < np) ? partial[i] : 0;
        sT[tid] = v;
        __syncthreads();
        for (int off = 1; off < 256; off <<= 1) {
            int x = (tid >= off) ? sT[tid - off] : 0;
            __syncthreads();
            sT[tid] += x;
            __syncthreads();
        }
        int incl = sT[tid];
        int total = sT[255];
        if (i < np) partial[i] = carry + incl - v;
        __syncthreads();
        if (tid == 0) carry += total;
        __syncthreads();
    }
}

// rowptr[i] = excl[i] + partial[i>>10]   (rank-based scatter needs no cursor)
__global__ void scan3m_kernel(const int* __restrict__ ew, const int* __restrict__ pw,
                              int* __restrict__ rw, int nw, int nbw,
                              const int* __restrict__ et, const int* __restrict__ pt,
                              int* __restrict__ rt, int nt) {
    int b = blockIdx.x;
    const int* excl; const int* partial; int* rp; int n; int i;
    if (b < nbw) { i = b * 256 + threadIdx.x; excl = ew; partial = pw; rp = rw; n = nw; }
    else { i = (b - nbw) * 256 + threadIdx.x; excl = et; partial = pt; rp = rt; n = nt; }
    if (i < n) rp[i] = excl[i] + partial[i >> 10];
}

// ======================= proj bodies (for the fused front) ===================
// F=64 MFMA body: LDS-free per-wave streaming with next-group prefetch.
// Output stores are NON-TEMPORAL (streamed once, never re-read this pass)
// so they don't evict the L2/L3 working sets.
__device__ __forceinline__ void proj64_body(const float* __restrict__ x,
                                            const float* __restrict__ W,
                                            const float* __restrict__ b,
                                            bf16* __restrict__ out, int n, int bid) {
    int tid = threadIdx.x;
    int lane = tid & 63, w = tid >> 6;
    int lm = lane & 15, lq = lane >> 4;

    bf16x8 wc[4][2];
    float bv[4];
#pragma unroll
    for (int ct = 0; ct < 4; ++ct) {
        int colc = ct * 16 + lm;
        wc[ct][0] = load_bfrag(W, lq * 8, colc);
        wc[ct][1] = load_bfrag(W, 32 + lq * 8, colc);
        bv[ct] = b[colc];
    }

    int larow = w * 16 + lm;
    int row0 = bid * 512;
    if (row0 >= n) return;
    int ar = row0 + larow; ar = (ar < n) ? ar : (n - 1);
    const float* xrow = x + ((size_t)ar << 6);
    float4 p0 = *(const float4*)(xrow + lq * 8);
    float4 p1 = *(const float4*)(xrow + lq * 8 + 4);
    float4 p2 = *(const float4*)(xrow + 32 + lq * 8);
    float4 p3 = *(const float4*)(xrow + 32 + lq * 8 + 4);

    for (int g = 0; g < 8; ++g) {
        int gr0 = row0 + g * 64;
        if (gr0 >= n) break;
        float4 q0 = p0, q1 = p1, q2 = p2, q3 = p3;
        if (g < 7) {   // prefetch next group
            int nr = gr0 + 64 + larow; nr = (nr < n) ? nr : (n - 1);
            const float* nx = x + ((size_t)nr << 6);
            q0 = *(const float4*)(nx + lq * 8);
            q1 = *(const float4*)(nx + lq * 8 + 4);
            q2 = *(const float4*)(nx + 32 + lq * 8);
            q3 = *(const float4*)(nx + 32 + lq * 8 + 4);
        }
        bf16x8 a0, a1;
        a0[0] = (short)f2bb(p0.x); a0[1] = (short)f2bb(p0.y);
        a0[2] = (short)f2bb(p0.z); a0[3] = (short)f2bb(p0.w);
        a0[4] = (short)f2bb(p1.x); a0[5] = (short)f2bb(p1.y);
        a0[6] = (short)f2bb(p1.z); a0[7] = (short)f2bb(p1.w);
        a1[0] = (short)f2bb(p2.x); a1[1] = (short)f2bb(p2.y);
        a1[2] = (short)f2bb(p2.z); a1[3] = (short)f2bb(p2.w);
        a1[4] = (short)f2bb(p3.x); a1[5] = (short)f2bb(p3.y);
        a1[6] = (short)f2bb(p3.z); a1[7] = (short)f2bb(p3.w);
#pragma unroll
        for (int ct = 0; ct < 4; ++ct) {
            f32x4 acc = {0.f, 0.f, 0.f, 0.f};
            acc = mfma16(a0, wc[ct][0], acc);
            acc = mfma16(a1, wc[ct][1], acc);
            int colc = ct * 16 + lm;
#pragma unroll
            for (int r = 0; r < 4; ++r) {
                int grow = gr0 + w * 16 + lq * 4 + r;
                if (grow < n)
                    __builtin_nontemporal_store(f2bb(acc[r] + bv[ct]),
                        (unsigned short*)&out[(size_t)grow * 64 + colc]);
            }
        }
        p0 = q0; p1 = q1; p2 = q2; p3 = q3;
    }
}

// F=32 VALU body (round-3 proven shape), shared tiles passed in.
__device__ __forceinline__ void proj32_body(const float* __restrict__ x,
                                            const float* __restrict__ W,
                                            const float* __restrict__ b,
                                            bf16* __restrict__ out, int n, int bid,
                                            float (*sW)[64], float* sb, float (*sx)[32]) {
    const int F = 32;
    int tid = threadIdx.x;
    for (int idx = tid; idx < F * 16; idx += 256)
        ((float4*)sW)[idx] = ((const float4*)W)[idx];
    if (tid < 64) sb[tid] = b[tid];
    int base = bid * 64;
    int w = tid >> 6, j = tid & 63;
    int lw = w * 4;
    for (int g = 0; g < 4; ++g) {
        int row0 = base + g * 16;
        __syncthreads();
        for (int idx = tid; idx < 4 * F; idx += 256) {
            int rr = idx / (F / 4), c4 = idx - rr * (F / 4);
            int row = row0 + rr;
            float4 v = (row < n) ? ((const float4*)x)[(size_t)row * (F / 4) + c4]
                                 : make_float4(0.f, 0.f, 0.f, 0.f);
            *(float4*)&sx[rr][c4 * 4] = v;
        }
        __syncthreads();
        float a0 = sb[j], a1 = sb[j], a2 = sb[j], a3 = sb[j];
#pragma unroll 2
        for (int k = 0; k < F; k += 4) {
            float w0 = sW[k][j], w1 = sW[k + 1][j], w2 = sW[k + 2][j], w3 = sW[k + 3][j];
            float4 m0 = *(const float4*)&sx[lw + 0][k];
            float4 m1 = *(const float4*)&sx[lw + 1][k];
            float4 m2 = *(const float4*)&sx[lw + 2][k];
            float4 m3 = *(const float4*)&sx[lw + 3][k];
            a0 += m0.x * w0 + m0.y * w1 + m0.z * w2 + m0.w * w3;
            a1 += m1.x * w0 + m1.y * w1 + m1.z * w2 + m1.w * w3;
            a2 += m2.x * w0 + m2.y * w1 + m2.z * w2 + m2.w * w3;
            a3 += m3.x * w0 + m3.y * w1 + m3.z * w2 + m3.w * w3;
        }
        int r0 = row0 + lw;
        if (r0 + 0 < n) __builtin_nontemporal_store(f2bb(a0),
                            (unsigned short*)&out[(size_t)(r0 + 0) * 64 + j]);
        if (r0 + 1 < n) __builtin_nontemporal_store(f2bb(a1),
                            (unsigned short*)&out[(size_t)(r0 + 1) * 64 + j]);
        if (r0 + 2 < n) __builtin_nontemporal_store(f2bb(a2),
                            (unsigned short*)&out[(size_t)(r0 + 2) * 64 + j]);
        if (r0 + 3 < n) __builtin_nontemporal_store(f2bb(a3),
                            (unsigned short*)&out[(size_t)(r0 + 3) * 64 + j]);
    }
}

// ======================= fused front: scatter + proj64 + proj32 ==============
__global__ __launch_bounds__(256)
void fused_front_kernel(const int* __restrict__ src_tw, const int* __restrict__ dst_tw,
                        const int* __restrict__ rank_tw, const int* __restrict__ rp_w,
                        int* __restrict__ col_tw, int ne_tw,
                        const int* __restrict__ src_wt, const int* __restrict__ dst_wt,
                        const int* __restrict__ rank_wt, const int* __restrict__ rp_tx,
                        int* __restrict__ col_wt, int ne_wt, int gsc,
                        const float* __restrict__ x_tx, const float* __restrict__ Win_tx,
                        const float* __restrict__ bin_tx, bf16* __restrict__ A, int n_tx, int gp64,
                        const float* __restrict__ x_w, const float* __restrict__ Win_w,
                        const float* __restrict__ bin_w, bf16* __restrict__ B, int n_w) {
    __shared__ float sW32[32][64];
    __shared__ float sb32[64];
    __shared__ float sx32[16][32];
    int bid = blockIdx.x;
    if (bid < gsc) {
        int e = bid * 256 + threadIdx.x;
        if (e < ne_tw) {
            col_tw[rp_w[dst_tw[e]] + rank_tw[e]] = src_tw[e];
        } else {
            int e2 = e - ne_tw;
            if (e2 < ne_wt)
                col_wt[rp_tx[dst_wt[e2]] + rank_wt[e2]] = src_wt[e2];
        }
    } else if (bid < gsc + gp64) {
        proj64_body(x_tx, Win_tx, bin_tx, A, n_tx, bid - gsc);
    } else {
        proj32_body(x_w, Win_w, bin_w, B, n_w, bid - gsc - gp64, sW32, sb32, sx32);
    }
}

// ======== FUSED gather + SAGE (MFMA; weights in LDS; NT output stores) ======
// out[i,j] = relu( mean_i . Wl[:,j] + bl[j] + xd[i,:] . Wr[:,j] ),
//   mean_i = (1/max(deg_i,1)) * sum_{e in CSR row i} hsrc[col[e], :]
// r16/r18-proven structure (1289us): bf16 B-fragments staged once per block
// into LDS, conflict-free contiguous ds_read_b128; gather fully IN-LANE,
// no barriers in the group loop; mean never touches HBM. NEW (r19): the big
// streaming output stores (outf 320MB f32 / outb 160MB bf16) are NON-TEMPORAL
// so they stop evicting the L3-resident gather sources (A/B or A2/B2,
// 160MB < 256MB L3) -> gather misses to HBM shrink. Values bit-identical.
#define GA4(x, wt) \
    p0 += (wt) * b2fx(x, 0); p1 += (wt) * b2fx(x, 1); \
    p2 += (wt) * b2fx(x, 2); p3 += (wt) * b2fx(x, 3); \
    p4 += (wt) * b2fx(x, 4); p5 += (wt) * b2fx(x, 5); \
    p6 += (wt) * b2fx(x, 6); p7 += (wt) * b2fx(x, 7);
#define GB4(x, wt) \
    q0 += (wt) * b2fx(x, 0); q1 += (wt) * b2fx(x, 1); \
    q2 += (wt) * b2fx(x, 2); q3 += (wt) * b2fx(x, 3); \
    q4 += (wt) * b2fx(x, 4); q5 += (wt) * b2fx(x, 5); \
    q6 += (wt) * b2fx(x, 6); q7 += (wt) * b2fx(x, 7);

template<bool HEAD>
__device__ __forceinline__ void sageg_body(
        const bf16* __restrict__ hsrc, const int* __restrict__ rowptr,
        const int* __restrict__ deg, const int* __restrict__ col,
        const bf16* __restrict__ xd,
        const float* __restrict__ Wl, const float* __restrict__ bl,
        const float* __restrict__ Wr,
        float* __restrict__ outf, bf16* __restrict__ outb,
        const float* __restrict__ Wh1, const float* __restrict__ bh1,
        const float* __restrict__ Wh2, const float* __restrict__ bh2,
        float* __restrict__ logits, int n, int bid, short* sW, short* sH) {
    int tid = threadIdx.x;
    int lane = tid & 63, w = tid >> 6;
    int lm = lane & 15, lq = lane >> 4;

    // --- stage bf16 weight fragments into LDS (once per block, one barrier) ---
    {
        int nfrag = HEAD ? 24 : 16;
        for (int idx = tid; idx < nfrag * 64; idx += 256) {
            int fid = idx >> 6, ln = idx & 63;
            int m = fid >> 3, ct = (fid >> 1) & 3, ks = fid & 1;
            const float* W = (m == 0) ? Wl : (m == 1) ? Wr : Wh1;
            bf16x8 f = load_bfrag(W, ks * 32 + (ln >> 4) * 8, ct * 16 + (ln & 15));
            *(bf16x8*)(sW + ((size_t)idx << 3)) = f;
        }
        __syncthreads();
    }
    const bf16x8* wfr = (const bf16x8*)sW;   // fragment (fid,lane) -> wfr[fid*64+lane]

    float blv[4], h1v[4], w2a[4], w2b[4];
#pragma unroll
    for (int ct = 0; ct < 4; ++ct) {
        int colc = ct * 16 + lm;
        blv[ct] = bl[colc];
        if (HEAD) {
            h1v[ct] = bh1[colc];
            w2a[ct] = Wh2[colc * 2 + 0];
            w2b[ct] = Wh2[colc * 2 + 1];
        }
    }
    float b20 = 0.f, b21 = 0.f;
    if (HEAD) { b20 = bh2[0]; b21 = bh2[1]; }

    int larow = w * 16 + lm;             // local A-fragment row (0..63)
    int row0 = bid * 512;
    if (row0 >= n) return;
    int fo1 = lq * 8, fo2 = 32 + lq * 8; // this lane's two feature octets

    // preload group 0's CSR row descriptor
    int ar0 = row0 + larow; ar0 = (ar0 < n) ? ar0 : (n - 1);
    int base = rowptr[ar0];
    int d = deg[ar0];

    for (int g = 0; g < 8; ++g) {
        int gr0 = row0 + g * 64;
        if (gr0 >= n) break;
        int arow = gr0 + larow;
        int ar = (arow < n) ? arow : (n - 1);
        // prefetch next group's rowptr/deg (one latency hop off next chain)
        int nbase = base, nd = d;
        if (g < 7) {
            int nr = gr0 + 64 + larow; nr = (nr < n) ? nr : (n - 1);
            nbase = rowptr[nr];
            nd = deg[nr];
        }
        // xd fragments: issue early so they're in flight during the gather
        const bf16* xrow = xd + ((size_t)ar << 6);
        bf16x8 a2 = *(const bf16x8*)(xrow + fo1);
        bf16x8 a3 = *(const bf16x8*)(xrow + fo2);
        // in-lane gather of row ar's two mean octets
        int lasto = (d > 0) ? d - 1 : 0;
        float p0 = 0.f, p1 = 0.f, p2 = 0.f, p3 = 0.f;
        float p4 = 0.f, p5 = 0.f, p6 = 0.f, p7 = 0.f;
        float q0 = 0.f, q1 = 0.f, q2 = 0.f, q3 = 0.f;
        float q4 = 0.f, q5 = 0.f, q6 = 0.f, q7 = 0.f;
        for (int e0 = 0; e0 < d; e0 += 4) {
            int o1 = (e0 + 1 < d) ? e0 + 1 : lasto;
            int o2 = (e0 + 2 < d) ? e0 + 2 : lasto;
            int o3 = (e0 + 3 < d) ? e0 + 3 : lasto;
            int s0 = col[base + e0], s1 = col[base + o1];
            int s2 = col[base + o2], s3 = col[base + o3];
            const bf16* r0p = hsrc + ((size_t)s0 << 6);
            const bf16* r1p = hsrc + ((size_t)s1 << 6);
            const bf16* r2p = hsrc + ((size_t)s2 << 6);
            const bf16* r3p = hsrc + ((size_t)s3 << 6);
            bf16x8 xa0 = *(const bf16x8*)(r0p + fo1);
            bf16x8 xb0 = *(const bf16x8*)(r0p + fo2);
            bf16x8 xa1 = *(const bf16x8*)(r1p + fo1);
            bf16x8 xb1 = *(const bf16x8*)(r1p + fo2);
            bf16x8 xa2 = *(const bf16x8*)(r2p + fo1);
            bf16x8 xb2 = *(const bf16x8*)(r2p + fo2);
            bf16x8 xa3 = *(const bf16x8*)(r3p + fo1);
            bf16x8 xb3 = *(const bf16x8*)(r3p + fo2);
            float w1 = (e0 + 1 < d) ? 1.f : 0.f;
            float w2 = (e0 + 2 < d) ? 1.f : 0.f;
            float w3 = (e0 + 3 < d) ? 1.f : 0.f;
            GA4(xa0, 1.f) GB4(xb0, 1.f)
            GA4(xa1, w1)  GB4(xb1, w1)
            GA4(xa2, w2)  GB4(xb2, w2)
            GA4(xa3, w3)  GB4(xb3, w3)
        }
        float dd = fmaxf((float)d, 1.f);
        bf16x8 a0, a1;
        a0[0] = (short)f2bb(p0 / dd); a0[1] = (short)f2bb(p1 / dd);
        a0[2] = (short)f2bb(p2 / dd); a0[3] = (short)f2bb(p3 / dd);
        a0[4] = (short)f2bb(p4 / dd); a0[5] = (short)f2bb(p5 / dd);
        a0[6] = (short)f2bb(p6 / dd); a0[7] = (short)f2bb(p7 / dd);
        a1[0] = (short)f2bb(q0 / dd); a1[1] = (short)f2bb(q1 / dd);
        a1[2] = (short)f2bb(q2 / dd); a1[3] = (short)f2bb(q3 / dd);
        a1[4] = (short)f2bb(q4 / dd); a1[5] = (short)f2bb(q5 / dd);
        a1[6] = (short)f2bb(q6 / dd); a1[7] = (short)f2bb(q7 / dd);

#pragma unroll
        for (int ct = 0; ct < 4; ++ct) {
            bf16x8 f0 = wfr[(ct * 2 + 0) * 64 + lane];          // Wl ks0
            bf16x8 f1 = wfr[(ct * 2 + 1) * 64 + lane];          // Wl ks1
            bf16x8 f2 = wfr[(8 + ct * 2 + 0) * 64 + lane];      // Wr ks0
            bf16x8 f3 = wfr[(8 + ct * 2 + 1) * 64 + lane];      // Wr ks1
            f32x4 acc = {0.f, 0.f, 0.f, 0.f};
            acc = mfma16(a0, f0, acc);
            acc = mfma16(a1, f1, acc);
            acc = mfma16(a2, f2, acc);
            acc = mfma16(a3, f3, acc);
            int colc = ct * 16 + lm;
#pragma unroll
            for (int r = 0; r < 4; ++r) {
                int lrow = w * 16 + lq * 4 + r;
                int grow = gr0 + lrow;
                float v = fmaxf(acc[r] + blv[ct], 0.f);
                if (grow < n) {
                    if (outf) __builtin_nontemporal_store(v,
                                  &outf[(size_t)grow * 64 + colc]);
                    if (outb) __builtin_nontemporal_store(f2bb(v),
                                  (unsigned short*)&outb[(size_t)grow * 64 + colc]);
                }
                if (HEAD)   // wave-local restage; same wave reads below
                    *(short*)((char*)sH + swzH(lrow, colc * 2)) = (short)f2bb(v);
            }
        }
        if (HEAD) {
            bf16x8 h0 = *(const bf16x8*)((char*)sH + swzH(larow, lq * 16));
            bf16x8 h1 = *(const bf16x8*)((char*)sH + swzH(larow, 64 + lq * 16));
            float qa0 = 0.f, qa1 = 0.f, qa2 = 0.f, qa3 = 0.f;
            float qb0 = 0.f, qb1 = 0.f, qb2 = 0.f, qb3 = 0.f;
#pragma unroll
            for (int ct = 0; ct < 4; ++ct) {
                bf16x8 g0 = wfr[(16 + ct * 2 + 0) * 64 + lane]; // Wh1 ks0
                bf16x8 g1 = wfr[(16 + ct * 2 + 1) * 64 + lane]; // Wh1 ks1
                f32x4 acc = {0.f, 0.f, 0.f, 0.f};
                acc = mfma16(h0, g0, acc);
                acc = mfma16(h1, g1, acc);
                float hb = h1v[ct];
                float h_0 = fmaxf(acc[0] + hb, 0.f);
                float h_1 = fmaxf(acc[1] + hb, 0.f);
                float h_2 = fmaxf(acc[2] + hb, 0.f);
                float h_3 = fmaxf(acc[3] + hb, 0.f);
                qa0 += h_0 * w2a[ct]; qb0 += h_0 * w2b[ct];
                qa1 += h_1 * w2a[ct]; qb1 += h_1 * w2b[ct];
                qa2 += h_2 * w2a[ct]; qb2 += h_2 * w2b[ct];
                qa3 += h_3 * w2a[ct]; qb3 += h_3 * w2b[ct];
            }
#pragma unroll
            for (int m = 8; m; m >>= 1) {   // reduce over the 16-lane quad
                qa0 += __shfl_xor(qa0, m); qb0 += __shfl_xor(qb0, m);
                qa1 += __shfl_xor(qa1, m); qb1 += __shfl_xor(qb1, m);
                qa2 += __shfl_xor(qa2, m); qb2 += __shfl_xor(qb2, m);
                qa3 += __shfl_xor(qa3, m); qb3 += __shfl_xor(qb3, m);
            }
            int rowb = gr0 + w * 16 + lq * 4;
            if (lm == 0) {
                if (rowb + 0 < n) { logits[(size_t)(rowb + 0) * 2 + 0] = qa0 + b20;
                                    logits[(size_t)(rowb + 0) * 2 + 1] = qb0 + b21; }
                if (rowb + 1 < n) { logits[(size_t)(rowb + 1) * 2 + 0] = qa1 + b20;
                                    logits[(size_t)(rowb + 1) * 2 + 1] = qb1 + b21; }
                if (rowb + 2 < n) { logits[(size_t)(rowb + 2) * 2 + 0] = qa2 + b20;
                                    logits[(size_t)(rowb + 2) * 2 + 1] = qb2 + b21; }
                if (rowb + 3 < n) { logits[(size_t)(rowb + 3) * 2 + 0] = qa3 + b20;
                                    logits[(size_t)(rowb + 3) * 2 + 1] = qb3 + b21; }
            }
        }
        base = nbase; d = nd;
    }
}

// Merged: blocks [0,gbw) run the wallet job (never HEAD), rest run the tx job.
template<bool HEAD>
__global__ __launch_bounds__(256)
void sageg2_kernel(const bf16* __restrict__ hw, const int* __restrict__ rpw,
                   const int* __restrict__ dgw, const int* __restrict__ clw,
                   const bf16* __restrict__ xw,
                   const float* __restrict__ Wlw, const float* __restrict__ blw,
                   const float* __restrict__ Wrw,
                   float* __restrict__ outfw, bf16* __restrict__ outbw, int nw, int gbw,
                   const bf16* __restrict__ ht, const int* __restrict__ rpt,
                   const int* __restrict__ dgt, const int* __restrict__ clt,
                   const bf16* __restrict__ xt,
                   const float* __restrict__ Wlt, const float* __restrict__ blt,
                   const float* __restrict__ Wrt,
                   float* __restrict__ outft, bf16* __restrict__ outbt,
                   const float* __restrict__ Wh1, const float* __restrict__ bh1,
                   const float* __restrict__ Wh2, const float* __restrict__ bh2,
                   float* __restrict__ logits, int nt) {
    __shared__ __align__(16) short sW[(HEAD ? 24 : 16) * 64 * 8];   // 16/24 KB
    __shared__ __align__(16) short sH[HEAD ? 64 * 64 : 8];          //  8 KB (HEAD)
    if ((int)blockIdx.x < gbw)
        sageg_body<false>(hw, rpw, dgw, clw, xw, Wlw, blw, Wrw, outfw, outbw,
                          nullptr, nullptr, nullptr, nullptr, nullptr, nw, blockIdx.x, sW, sH);
    else
        sageg_body<HEAD>(ht, rpt, dgt, clt, xt, Wlt, blt, Wrt, outft, outbt,
                         Wh1, bh1, Wh2, bh2, logits, nt, blockIdx.x - gbw, sW, sH);
}

extern "C" void kernel_launch(void* const* d_in, const int* in_sizes, int n_in,
                              void* d_out, int out_size, void* d_ws, size_t ws_size,
                              hipStream_t stream) {
    const float* x_tx   = (const float*)d_in[0];
    const float* x_w    = (const float*)d_in[1];
    const int*   src_tw = (const int*)d_in[2];
    const int*   dst_tw = (const int*)d_in[3];
    const int*   src_wt = (const int*)d_in[4];
    const int*   dst_wt = (const int*)d_in[5];
    const float* Win_tx = (const float*)d_in[6];
    const float* bin_tx = (const float*)d_in[7];
    const float* Win_w  = (const float*)d_in[8];
    const float* bin_w  = (const float*)d_in[9];
    const float* Wl1_tw = (const float*)d_in[10];
    const float* bl1_tw = (const float*)d_in[11];
    const float* Wr1_tw = (const float*)d_in[12];
    const float* Wl1_wt = (const float*)d_in[13];
    const float* bl1_wt = (const float*)d_in[14];
    const float* Wr1_wt = (const float*)d_in[15];
    const float* Wl2_tw = (const float*)d_in[16];
    const float* bl2_tw = (const float*)d_in[17];
    const float* Wr2_tw = (const float*)d_in[18];
    const float* Wl2_wt = (const float*)d_in[19];
    const float* bl2_wt = (const float*)d_in[20];
    const float* Wr2_wt = (const float*)d_in[21];
    const float* Wh1    = (const float*)d_in[22];
    const float* bh1    = (const float*)d_in[23];
    const float* Wh2    = (const float*)d_in[24];
    const float* bh2    = (const float*)d_in[25];

    const int n_tx  = in_sizes[0] / 64;
    const int n_w   = in_sizes[1] / 32;
    const int ne_tw = in_sizes[2];
    const int ne_wt = in_sizes[4];

    // ---- workspace layout (~367 MB); A2/B2 are the conv ping-pong targets ----
    bf16* A2      = (bf16*)d_ws;                          // n_tx*64 bf16: t1
    bf16* B2      = A2 + (size_t)n_tx * 64;               // n_w *64 bf16: w1
    bf16* A       = B2 + (size_t)n_w * 64;                // n_tx*64 bf16: h_tx
    bf16* B       = A + (size_t)n_tx * 64;                // n_w *64 bf16: h_w
    int*  deg_w   = (int*)(B + (size_t)n_w * 64);         // n_w
    int*  deg_tx  = deg_w + n_w;                          // n_tx
    int*  rp_w    = deg_tx + n_tx;                        // n_w
    int*  rp_tx   = rp_w + n_w;                           // n_tx
    int*  ex_w    = rp_tx + n_tx;                         // n_w  (scan scratch)
    int*  ex_tx   = ex_w + n_w;                           // n_tx
    int*  col_tw  = ex_tx + n_tx;                         // ne_tw
    int*  col_wt  = col_tw + ne_tw;                       // ne_wt
    int*  rank_tw = col_wt + ne_wt;                       // ne_tw
    int*  rank_wt = rank_tw + ne_tw;                      // ne_wt
    int*  part_w  = rank_wt + ne_wt;                      // <=4096
    int*  part_tx = part_w + 4096;                        // <=4096

    float* out_logits = (float*)d_out;
    float* out_t2 = out_logits + (size_t)n_tx * 2;
    float* out_w2 = out_t2 + (size_t)n_tx * 64;

    dim3 blk(256);
    int gp64 = (n_tx + 511) / 512;
    int gp32 = (n_w + 63) / 64;
    int gs_w  = (n_w + 511) / 512;
    int gs_tx = (n_tx + 511) / 512;
    int gsc = (ne_tw + ne_wt + 255) / 256;
    int gcr = (ne_tw + ne_wt + 511) / 512;   // count_rank: 2 edges/thread
    int np_w  = (n_w + 1023) / 1024;
    int np_tx = (n_tx + 1023) / 1024;
    int nbw = (n_w + 255) / 256;
    int nbt = (n_tx + 255) / 256;

    // ---- CSR build: count+rank, scans (graph static, reused by both convs) ----
    hipMemsetAsync(deg_w, 0, (size_t)n_w * sizeof(int), stream);
    hipMemsetAsync(deg_tx, 0, (size_t)n_tx * sizeof(int), stream);
    count_rank2_kernel<<<gcr, blk, 0, stream>>>(dst_tw, deg_w, rank_tw, ne_tw,
                                                dst_wt, deg_tx, rank_wt, ne_wt);
    scan1m_kernel<<<np_w + np_tx, blk, 0, stream>>>(deg_w, ex_w, part_w, n_w, np_w,
                                                    deg_tx, ex_tx, part_tx, n_tx);
    scan2m_kernel<<<2, blk, 0, stream>>>(part_w, np_w, part_tx, np_tx);
    scan3m_kernel<<<nbw + nbt, blk, 0, stream>>>(ex_w, part_w, rp_w, n_w, nbw,
                                                 ex_tx, part_tx, rp_tx, n_tx);

    // ---- fused front: rank-scatter (no atomics) + proj64 + proj32, one launch ----
    fused_front_kernel<<<gsc + gp64 + gp32, blk, 0, stream>>>(
        src_tw, dst_tw, rank_tw, rp_w, col_tw, ne_tw,
        src_wt, dst_wt, rank_wt, rp_tx, col_wt, ne_wt, gsc,
        x_tx, Win_tx, bin_tx, A, n_tx, gp64,
        x_w, Win_w, bin_w, B, n_w);

    // ---- conv1 (fused gather+GEMM; reads A,B only, writes A2,B2) ----
    sageg2_kernel<false><<<gs_w + gs_tx, blk, 0, stream>>>(
        A, rp_w, deg_w, col_tw, B, Wl1_tw, bl1_tw, Wr1_tw, nullptr, B2, n_w, gs_w,
        B, rp_tx, deg_tx, col_wt, A, Wl1_wt, bl1_wt, Wr1_wt, nullptr, A2,
        nullptr, nullptr, nullptr, nullptr, nullptr, n_tx);

    // ---- conv2 (fused; reads A2,B2, writes f32 outputs; tx has HEAD) ----
    sageg2_kernel<true><<<gs_w + gs_tx, blk, 0, stream>>>(
        A2, rp_w, deg_w, col_tw, B2, Wl2_tw, bl2_tw, Wr2_tw, out_w2, nullptr, n_w, gs_w,
        B2, rp_tx, deg_tx, col_wt, A2, Wl2_wt, bl2_wt, Wr2_wt, out_t2, nullptr,
        Wh1, bh1, Wh2, bh2, out_logits, n_tx);
}

// Round 20
// 1288.337 us; speedup vs baseline: 1.1346x; 1.1346x over previous
//
#include <hip/hip_runtime.h>
#include <hip/hip_bf16.h>

typedef __hip_bfloat16 bf16;
typedef __attribute__((ext_vector_type(8))) short bf16x8;   // 8 bf16 = 4 VGPR
typedef __attribute__((ext_vector_type(4))) float f32x4;    // MFMA accumulator

__device__ __forceinline__ float b2f(bf16 v) { return __bfloat162float(v); }
__device__ __forceinline__ bf16 f2b(float v) { return __float2bfloat16(v); }
__device__ __forceinline__ unsigned short f2bb(float v) {   // RNE f32->bf16 bits
    unsigned int u = __float_as_uint(v);
    u += 0x7fffu + ((u >> 16) & 1u);
    return (unsigned short)(u >> 16);
}
// bf16x8 element k (compile-time k) -> f32 via bit shift
__device__ __forceinline__ float b2fx(bf16x8 v, int k) {
    return __uint_as_float(((unsigned int)(unsigned short)v[k]) << 16);
}

__device__ __forceinline__ f32x4 mfma16(bf16x8 a, bf16x8 b, f32x4 c) {
    return __builtin_amdgcn_mfma_f32_16x16x32_bf16(a, b, c, 0, 0, 0);
}

// Gather a B-fragment: rows k0..k0+7 of column col from row-major W[64][64] f32.
__device__ __forceinline__ bf16x8 load_bfrag(const float* __restrict__ W, int k0, int col) {
    bf16x8 f;
#pragma unroll
    for (int j = 0; j < 8; ++j)
        f[j] = (short)f2bb(W[(size_t)(k0 + j) * 64 + col]);
    return f;
}

// Swizzled byte offset for the HEAD restage tile ([64][64 bf16], 128B rows).
__device__ __forceinline__ int swzH(int row, int b) {
    return row * 128 + (b ^ ((row & 7) << 4));
}

// ======================= CSR build =======================
__device__ __forceinline__ void cr_one(int e,
        const int* __restrict__ dst_tw, int* __restrict__ deg_w,
        int* __restrict__ rank_tw, int ne_tw,
        const int* __restrict__ dst_wt, int* __restrict__ deg_tx,
        int* __restrict__ rank_wt, int ne_wt) {
    if (e < ne_tw) rank_tw[e] = atomicAdd(&deg_w[dst_tw[e]], 1);
    else {
        int e2 = e - ne_tw;
        if (e2 < ne_wt) rank_wt[e2] = atomicAdd(&deg_tx[dst_wt[e2]], 1);
    }
}
__global__ void count_rank2_kernel(const int* __restrict__ dst_tw, int* __restrict__ deg_w,
                                   int* __restrict__ rank_tw, int ne_tw,
                                   const int* __restrict__ dst_wt, int* __restrict__ deg_tx,
                                   int* __restrict__ rank_wt, int ne_wt) {
    int t = blockIdx.x * 256 + threadIdx.x;
    cr_one(t * 2 + 0, dst_tw, deg_w, rank_tw, ne_tw, dst_wt, deg_tx, rank_wt, ne_wt);
    cr_one(t * 2 + 1, dst_tw, deg_w, rank_tw, ne_tw, dst_wt, deg_tx, rank_wt, ne_wt);
}

// block-local exclusive scan over 1024 elems (256 thr x 4); writes block totals
__global__ void scan1m_kernel(const int* __restrict__ dw, int* __restrict__ ew,
                              int* __restrict__ pw, int nw, int npw,
                              const int* __restrict__ dt, int* __restrict__ et,
                              int* __restrict__ pt, int nt) {
    __shared__ int sT[256];
    const int* deg; int* excl; int* partial; int n; int b;
    if ((int)blockIdx.x < npw) { deg = dw; excl = ew; partial = pw; n = nw; b = blockIdx.x; }
    else { deg = dt; excl = et; partial = pt; n = nt; b = blockIdx.x - npw; }
    int tid = threadIdx.x;
    int base = b * 1024 + tid * 4;
    int v0 = (base + 0 < n) ? deg[base + 0] : 0;
    int v1 = (base + 1 < n) ? deg[base + 1] : 0;
    int v2 = (base + 2 < n) ? deg[base + 2] : 0;
    int v3 = (base + 3 < n) ? deg[base + 3] : 0;
    int t = v0 + v1 + v2 + v3;
    sT[tid] = t;
    __syncthreads();
    for (int off = 1; off < 256; off <<= 1) {   // Hillis-Steele inclusive
        int x = (tid >= off) ? sT[tid - off] : 0;
        __syncthreads();
        sT[tid] += x;
        __syncthreads();
    }
    int et2 = sT[tid] - t;
    if (tid == 255) partial[b] = sT[255];
    if (base + 0 < n) excl[base + 0] = et2;
    if (base + 1 < n) excl[base + 1] = et2 + v0;
    if (base + 2 < n) excl[base + 2] = et2 + v0 + v1;
    if (base + 3 < n) excl[base + 3] = et2 + v0 + v1 + v2;
}

// block 0 scans part_w, block 1 scans part_tx (each single-block full scan)
__global__ void scan2m_kernel(int* __restrict__ pw, int npw, int* __restrict__ pt, int npt) {
    __shared__ int sT[256];
    __shared__ int carry;
    int* partial = blockIdx.x ? pt : pw;
    int np = blockIdx.x ? npt : npw;
    int tid = threadIdx.x;
    if (tid == 0) carry = 0;
    __syncthreads();
    for (int c = 0; c < np; c += 256) {
        int i = c + tid;
        int v = (i < np) ? partial[i] : 0;
        sT[tid] = v;
        __syncthreads();
        for (int off = 1; off < 256; off <<= 1) {
            int x = (tid >= off) ? sT[tid - off] : 0;
            __syncthreads();
            sT[tid] += x;
            __syncthreads();
        }
        int incl = sT[tid];
        int total = sT[255];
        if (i < np) partial[i] = carry + incl - v;
        __syncthreads();
        if (tid == 0) carry += total;
        __syncthreads();
    }
}

// rowptr[i] = excl[i] + partial[i>>10]   (rank-based scatter needs no cursor)
__global__ void scan3m_kernel(const int* __restrict__ ew, const int* __restrict__ pw,
                              int* __restrict__ rw, int nw, int nbw,
                              const int* __restrict__ et, const int* __restrict__ pt,
                              int* __restrict__ rt, int nt) {
    int b = blockIdx.x;
    const int* excl; const int* partial; int* rp; int n; int i;
    if (b < nbw) { i = b * 256 + threadIdx.x; excl = ew; partial = pw; rp = rw; n = nw; }
    else { i = (b - nbw) * 256 + threadIdx.x; excl = et; partial = pt; rp = rt; n = nt; }
    if (i < n) rp[i] = excl[i] + partial[i >> 10];
}

// ======================= proj bodies (for the fused front) ===================
// F=64 MFMA body: LDS-free per-wave streaming with next-group prefetch.
__device__ __forceinline__ void proj64_body(const float* __restrict__ x,
                                            const float* __restrict__ W,
                                            const float* __restrict__ b,
                                            bf16* __restrict__ out, int n, int bid) {
    int tid = threadIdx.x;
    int lane = tid & 63, w = tid >> 6;
    int lm = lane & 15, lq = lane >> 4;

    bf16x8 wc[4][2];
    float bv[4];
#pragma unroll
    for (int ct = 0; ct < 4; ++ct) {
        int colc = ct * 16 + lm;
        wc[ct][0] = load_bfrag(W, lq * 8, colc);
        wc[ct][1] = load_bfrag(W, 32 + lq * 8, colc);
        bv[ct] = b[colc];
    }

    int larow = w * 16 + lm;
    int row0 = bid * 512;
    if (row0 >= n) return;
    int ar = row0 + larow; ar = (ar < n) ? ar : (n - 1);
    const float* xrow = x + ((size_t)ar << 6);
    float4 p0 = *(const float4*)(xrow + lq * 8);
    float4 p1 = *(const float4*)(xrow + lq * 8 + 4);
    float4 p2 = *(const float4*)(xrow + 32 + lq * 8);
    float4 p3 = *(const float4*)(xrow + 32 + lq * 8 + 4);

    for (int g = 0; g < 8; ++g) {
        int gr0 = row0 + g * 64;
        if (gr0 >= n) break;
        float4 q0 = p0, q1 = p1, q2 = p2, q3 = p3;
        if (g < 7) {   // prefetch next group
            int nr = gr0 + 64 + larow; nr = (nr < n) ? nr : (n - 1);
            const float* nx = x + ((size_t)nr << 6);
            q0 = *(const float4*)(nx + lq * 8);
            q1 = *(const float4*)(nx + lq * 8 + 4);
            q2 = *(const float4*)(nx + 32 + lq * 8);
            q3 = *(const float4*)(nx + 32 + lq * 8 + 4);
        }
        bf16x8 a0, a1;
        a0[0] = (short)f2bb(p0.x); a0[1] = (short)f2bb(p0.y);
        a0[2] = (short)f2bb(p0.z); a0[3] = (short)f2bb(p0.w);
        a0[4] = (short)f2bb(p1.x); a0[5] = (short)f2bb(p1.y);
        a0[6] = (short)f2bb(p1.z); a0[7] = (short)f2bb(p1.w);
        a1[0] = (short)f2bb(p2.x); a1[1] = (short)f2bb(p2.y);
        a1[2] = (short)f2bb(p2.z); a1[3] = (short)f2bb(p2.w);
        a1[4] = (short)f2bb(p3.x); a1[5] = (short)f2bb(p3.y);
        a1[6] = (short)f2bb(p3.z); a1[7] = (short)f2bb(p3.w);
#pragma unroll
        for (int ct = 0; ct < 4; ++ct) {
            f32x4 acc = {0.f, 0.f, 0.f, 0.f};
            acc = mfma16(a0, wc[ct][0], acc);
            acc = mfma16(a1, wc[ct][1], acc);
            int colc = ct * 16 + lm;
#pragma unroll
            for (int r = 0; r < 4; ++r) {
                int grow = gr0 + w * 16 + lq * 4 + r;
                if (grow < n)
                    out[(size_t)grow * 64 + colc] = f2b(acc[r] + bv[ct]);
            }
        }
        p0 = q0; p1 = q1; p2 = q2; p3 = q3;
    }
}

// F=32 VALU body (round-3 proven shape), shared tiles passed in.
__device__ __forceinline__ void proj32_body(const float* __restrict__ x,
                                            const float* __restrict__ W,
                                            const float* __restrict__ b,
                                            bf16* __restrict__ out, int n, int bid,
                                            float (*sW)[64], float* sb, float (*sx)[32]) {
    const int F = 32;
    int tid = threadIdx.x;
    for (int idx = tid; idx < F * 16; idx += 256)
        ((float4*)sW)[idx] = ((const float4*)W)[idx];
    if (tid < 64) sb[tid] = b[tid];
    int base = bid * 64;
    int w = tid >> 6, j = tid & 63;
    int lw = w * 4;
    for (int g = 0; g < 4; ++g) {
        int row0 = base + g * 16;
        __syncthreads();
        for (int idx = tid; idx < 4 * F; idx += 256) {
            int rr = idx / (F / 4), c4 = idx - rr * (F / 4);
            int row = row0 + rr;
            float4 v = (row < n) ? ((const float4*)x)[(size_t)row * (F / 4) + c4]
                                 : make_float4(0.f, 0.f, 0.f, 0.f);
            *(float4*)&sx[rr][c4 * 4] = v;
        }
        __syncthreads();
        float a0 = sb[j], a1 = sb[j], a2 = sb[j], a3 = sb[j];
#pragma unroll 2
        for (int k = 0; k < F; k += 4) {
            float w0 = sW[k][j], w1 = sW[k + 1][j], w2 = sW[k + 2][j], w3 = sW[k + 3][j];
            float4 m0 = *(const float4*)&sx[lw + 0][k];
            float4 m1 = *(const float4*)&sx[lw + 1][k];
            float4 m2 = *(const float4*)&sx[lw + 2][k];
            float4 m3 = *(const float4*)&sx[lw + 3][k];
            a0 += m0.x * w0 + m0.y * w1 + m0.z * w2 + m0.w * w3;
            a1 += m1.x * w0 + m1.y * w1 + m1.z * w2 + m1.w * w3;
            a2 += m2.x * w0 + m2.y * w1 + m2.z * w2 + m2.w * w3;
            a3 += m3.x * w0 + m3.y * w1 + m3.z * w2 + m3.w * w3;
        }
        int r0 = row0 + lw;
        if (r0 + 0 < n) out[(size_t)(r0 + 0) * 64 + j] = f2b(a0);
        if (r0 + 1 < n) out[(size_t)(r0 + 1) * 64 + j] = f2b(a1);
        if (r0 + 2 < n) out[(size_t)(r0 + 2) * 64 + j] = f2b(a2);
        if (r0 + 3 < n) out[(size_t)(r0 + 3) * 64 + j] = f2b(a3);
    }
}

// ======================= fused front: scatter + proj64 + proj32 ==============
__global__ __launch_bounds__(256)
void fused_front_kernel(const int* __restrict__ src_tw, const int* __restrict__ dst_tw,
                        const int* __restrict__ rank_tw, const int* __restrict__ rp_w,
                        int* __restrict__ col_tw, int ne_tw,
                        const int* __restrict__ src_wt, const int* __restrict__ dst_wt,
                        const int* __restrict__ rank_wt, const int* __restrict__ rp_tx,
                        int* __restrict__ col_wt, int ne_wt, int gsc,
                        const float* __restrict__ x_tx, const float* __restrict__ Win_tx,
                        const float* __restrict__ bin_tx, bf16* __restrict__ A, int n_tx, int gp64,
                        const float* __restrict__ x_w, const float* __restrict__ Win_w,
                        const float* __restrict__ bin_w, bf16* __restrict__ B, int n_w) {
    __shared__ float sW32[32][64];
    __shared__ float sb32[64];
    __shared__ float sx32[16][32];
    int bid = blockIdx.x;
    if (bid < gsc) {
        int e = bid * 256 + threadIdx.x;
        if (e < ne_tw) {
            col_tw[rp_w[dst_tw[e]] + rank_tw[e]] = src_tw[e];
        } else {
            int e2 = e - ne_tw;
            if (e2 < ne_wt)
                col_wt[rp_tx[dst_wt[e2]] + rank_wt[e2]] = src_wt[e2];
        }
    } else if (bid < gsc + gp64) {
        proj64_body(x_tx, Win_tx, bin_tx, A, n_tx, bid - gsc);
    } else {
        proj32_body(x_w, Win_w, bin_w, B, n_w, bid - gsc - gp64, sW32, sb32, sx32);
    }
}

// ======== FUSED gather + SAGE (MFMA; weights in LDS for occupancy) ========
// out[i,j] = relu( mean_i . Wl[:,j] + bl[j] + xd[i,:] . Wr[:,j] ),
//   mean_i = (1/max(deg_i,1)) * sum_{e in CSR row i} hsrc[col[e], :]
// Best-measured configuration (r16/r18, 1289us): per-lane bf16 B-fragments
// staged once per block into LDS (one barrier), read per col-tile with
// conflict-free contiguous ds_read_b128. VGPR ~72, occupancy ~29%. Gather
// fully IN-LANE (16 f32 accums), no barriers in the group loop; mean never
// touches HBM. Chunk-of-4 clamped edges + {0,1} weights. NOT in-place.
// HEAD: t2 restaged bf16 into sH (wave-local rows, per-wave LDS program
// order), K=64 MFMA GEMM + 16-lane shfl_xor reduce for the 64->2 contraction.
// NOTE (r19 falsified): NT stores on outputs REGRESS — proj/conv1 outputs are
// re-read by the following gathers and must stay cache-resident.
#define GA4(x, wt) \
    p0 += (wt) * b2fx(x, 0); p1 += (wt) * b2fx(x, 1); \
    p2 += (wt) * b2fx(x, 2); p3 += (wt) * b2fx(x, 3); \
    p4 += (wt) * b2fx(x, 4); p5 += (wt) * b2fx(x, 5); \
    p6 += (wt) * b2fx(x, 6); p7 += (wt) * b2fx(x, 7);
#define GB4(x, wt) \
    q0 += (wt) * b2fx(x, 0); q1 += (wt) * b2fx(x, 1); \
    q2 += (wt) * b2fx(x, 2); q3 += (wt) * b2fx(x, 3); \
    q4 += (wt) * b2fx(x, 4); q5 += (wt) * b2fx(x, 5); \
    q6 += (wt) * b2fx(x, 6); q7 += (wt) * b2fx(x, 7);

template<bool HEAD>
__device__ __forceinline__ void sageg_body(
        const bf16* __restrict__ hsrc, const int* __restrict__ rowptr,
        const int* __restrict__ deg, const int* __restrict__ col,
        const bf16* __restrict__ xd,
        const float* __restrict__ Wl, const float* __restrict__ bl,
        const float* __restrict__ Wr,
        float* __restrict__ outf, bf16* __restrict__ outb,
        const float* __restrict__ Wh1, const float* __restrict__ bh1,
        const float* __restrict__ Wh2, const float* __restrict__ bh2,
        float* __restrict__ logits, int n, int bid, short* sW, short* sH) {
    int tid = threadIdx.x;
    int lane = tid & 63, w = tid >> 6;
    int lm = lane & 15, lq = lane >> 4;

    // --- stage bf16 weight fragments into LDS (once per block, one barrier) ---
    {
        int nfrag = HEAD ? 24 : 16;
        for (int idx = tid; idx < nfrag * 64; idx += 256) {
            int fid = idx >> 6, ln = idx & 63;
            int m = fid >> 3, ct = (fid >> 1) & 3, ks = fid & 1;
            const float* W = (m == 0) ? Wl : (m == 1) ? Wr : Wh1;
            bf16x8 f = load_bfrag(W, ks * 32 + (ln >> 4) * 8, ct * 16 + (ln & 15));
            *(bf16x8*)(sW + ((size_t)idx << 3)) = f;
        }
        __syncthreads();
    }
    const bf16x8* wfr = (const bf16x8*)sW;   // fragment (fid,lane) -> wfr[fid*64+lane]

    float blv[4], h1v[4], w2a[4], w2b[4];
#pragma unroll
    for (int ct = 0; ct < 4; ++ct) {
        int colc = ct * 16 + lm;
        blv[ct] = bl[colc];
        if (HEAD) {
            h1v[ct] = bh1[colc];
            w2a[ct] = Wh2[colc * 2 + 0];
            w2b[ct] = Wh2[colc * 2 + 1];
        }
    }
    float b20 = 0.f, b21 = 0.f;
    if (HEAD) { b20 = bh2[0]; b21 = bh2[1]; }

    int larow = w * 16 + lm;             // local A-fragment row (0..63)
    int row0 = bid * 512;
    if (row0 >= n) return;
    int fo1 = lq * 8, fo2 = 32 + lq * 8; // this lane's two feature octets

    // preload group 0's CSR row descriptor
    int ar0 = row0 + larow; ar0 = (ar0 < n) ? ar0 : (n - 1);
    int base = rowptr[ar0];
    int d = deg[ar0];

    for (int g = 0; g < 8; ++g) {
        int gr0 = row0 + g * 64;
        if (gr0 >= n) break;
        int arow = gr0 + larow;
        int ar = (arow < n) ? arow : (n - 1);
        // prefetch next group's rowptr/deg (one latency hop off next chain)
        int nbase = base, nd = d;
        if (g < 7) {
            int nr = gr0 + 64 + larow; nr = (nr < n) ? nr : (n - 1);
            nbase = rowptr[nr];
            nd = deg[nr];
        }
        // xd fragments: issue early so they're in flight during the gather
        const bf16* xrow = xd + ((size_t)ar << 6);
        bf16x8 a2 = *(const bf16x8*)(xrow + fo1);
        bf16x8 a3 = *(const bf16x8*)(xrow + fo2);
        // in-lane gather of row ar's two mean octets
        int lasto = (d > 0) ? d - 1 : 0;
        float p0 = 0.f, p1 = 0.f, p2 = 0.f, p3 = 0.f;
        float p4 = 0.f, p5 = 0.f, p6 = 0.f, p7 = 0.f;
        float q0 = 0.f, q1 = 0.f, q2 = 0.f, q3 = 0.f;
        float q4 = 0.f, q5 = 0.f, q6 = 0.f, q7 = 0.f;
        for (int e0 = 0; e0 < d; e0 += 4) {
            int o1 = (e0 + 1 < d) ? e0 + 1 : lasto;
            int o2 = (e0 + 2 < d) ? e0 + 2 : lasto;
            int o3 = (e0 + 3 < d) ? e0 + 3 : lasto;
            int s0 = col[base + e0], s1 = col[base + o1];
            int s2 = col[base + o2], s3 = col[base + o3];
            const bf16* r0p = hsrc + ((size_t)s0 << 6);
            const bf16* r1p = hsrc + ((size_t)s1 << 6);
            const bf16* r2p = hsrc + ((size_t)s2 << 6);
            const bf16* r3p = hsrc + ((size_t)s3 << 6);
            bf16x8 xa0 = *(const bf16x8*)(r0p + fo1);
            bf16x8 xb0 = *(const bf16x8*)(r0p + fo2);
            bf16x8 xa1 = *(const bf16x8*)(r1p + fo1);
            bf16x8 xb1 = *(const bf16x8*)(r1p + fo2);
            bf16x8 xa2 = *(const bf16x8*)(r2p + fo1);
            bf16x8 xb2 = *(const bf16x8*)(r2p + fo2);
            bf16x8 xa3 = *(const bf16x8*)(r3p + fo1);
            bf16x8 xb3 = *(const bf16x8*)(r3p + fo2);
            float w1 = (e0 + 1 < d) ? 1.f : 0.f;
            float w2 = (e0 + 2 < d) ? 1.f : 0.f;
            float w3 = (e0 + 3 < d) ? 1.f : 0.f;
            GA4(xa0, 1.f) GB4(xb0, 1.f)
            GA4(xa1, w1)  GB4(xb1, w1)
            GA4(xa2, w2)  GB4(xb2, w2)
            GA4(xa3, w3)  GB4(xb3, w3)
        }
        float dd = fmaxf((float)d, 1.f);
        bf16x8 a0, a1;
        a0[0] = (short)f2bb(p0 / dd); a0[1] = (short)f2bb(p1 / dd);
        a0[2] = (short)f2bb(p2 / dd); a0[3] = (short)f2bb(p3 / dd);
        a0[4] = (short)f2bb(p4 / dd); a0[5] = (short)f2bb(p5 / dd);
        a0[6] = (short)f2bb(p6 / dd); a0[7] = (short)f2bb(p7 / dd);
        a1[0] = (short)f2bb(q0 / dd); a1[1] = (short)f2bb(q1 / dd);
        a1[2] = (short)f2bb(q2 / dd); a1[3] = (short)f2bb(q3 / dd);
        a1[4] = (short)f2bb(q4 / dd); a1[5] = (short)f2bb(q5 / dd);
        a1[6] = (short)f2bb(q6 / dd); a1[7] = (short)f2bb(q7 / dd);

#pragma unroll
        for (int ct = 0; ct < 4; ++ct) {
            bf16x8 f0 = wfr[(ct * 2 + 0) * 64 + lane];          // Wl ks0
            bf16x8 f1 = wfr[(ct * 2 + 1) * 64 + lane];          // Wl ks1
            bf16x8 f2 = wfr[(8 + ct * 2 + 0) * 64 + lane];      // Wr ks0
            bf16x8 f3 = wfr[(8 + ct * 2 + 1) * 64 + lane];      // Wr ks1
            f32x4 acc = {0.f, 0.f, 0.f, 0.f};
            acc = mfma16(a0, f0, acc);
            acc = mfma16(a1, f1, acc);
            acc = mfma16(a2, f2, acc);
            acc = mfma16(a3, f3, acc);
            int colc = ct * 16 + lm;
#pragma unroll
            for (int r = 0; r < 4; ++r) {
                int lrow = w * 16 + lq * 4 + r;
                int grow = gr0 + lrow;
                float v = fmaxf(acc[r] + blv[ct], 0.f);
                if (grow < n) {
                    if (outf) outf[(size_t)grow * 64 + colc] = v;
                    if (outb) outb[(size_t)grow * 64 + colc] = f2b(v);
                }
                if (HEAD)   // wave-local restage; same wave reads below
                    *(short*)((char*)sH + swzH(lrow, colc * 2)) = (short)f2bb(v);
            }
        }
        if (HEAD) {
            bf16x8 h0 = *(const bf16x8*)((char*)sH + swzH(larow, lq * 16));
            bf16x8 h1 = *(const bf16x8*)((char*)sH + swzH(larow, 64 + lq * 16));
            float qa0 = 0.f, qa1 = 0.f, qa2 = 0.f, qa3 = 0.f;
            float qb0 = 0.f, qb1 = 0.f, qb2 = 0.f, qb3 = 0.f;
#pragma unroll
            for (int ct = 0; ct < 4; ++ct) {
                bf16x8 g0 = wfr[(16 + ct * 2 + 0) * 64 + lane]; // Wh1 ks0
                bf16x8 g1 = wfr[(16 + ct * 2 + 1) * 64 + lane]; // Wh1 ks1
                f32x4 acc = {0.f, 0.f, 0.f, 0.f};
                acc = mfma16(h0, g0, acc);
                acc = mfma16(h1, g1, acc);
                float hb = h1v[ct];
                float h_0 = fmaxf(acc[0] + hb, 0.f);
                float h_1 = fmaxf(acc[1] + hb, 0.f);
                float h_2 = fmaxf(acc[2] + hb, 0.f);
                float h_3 = fmaxf(acc[3] + hb, 0.f);
                qa0 += h_0 * w2a[ct]; qb0 += h_0 * w2b[ct];
                qa1 += h_1 * w2a[ct]; qb1 += h_1 * w2b[ct];
                qa2 += h_2 * w2a[ct]; qb2 += h_2 * w2b[ct];
                qa3 += h_3 * w2a[ct]; qb3 += h_3 * w2b[ct];
            }
#pragma unroll
            for (int m = 8; m; m >>= 1) {   // reduce over the 16-lane quad
                qa0 += __shfl_xor(qa0, m); qb0 += __shfl_xor(qb0, m);
                qa1 += __shfl_xor(qa1, m); qb1 += __shfl_xor(qb1, m);
                qa2 += __shfl_xor(qa2, m); qb2 += __shfl_xor(qb2, m);
                qa3 += __shfl_xor(qa3, m); qb3 += __shfl_xor(qb3, m);
            }
            int rowb = gr0 + w * 16 + lq * 4;
            if (lm == 0) {
                if (rowb + 0 < n) { logits[(size_t)(rowb + 0) * 2 + 0] = qa0 + b20;
                                    logits[(size_t)(rowb + 0) * 2 + 1] = qb0 + b21; }
                if (rowb + 1 < n) { logits[(size_t)(rowb + 1) * 2 + 0] = qa1 + b20;
                                    logits[(size_t)(rowb + 1) * 2 + 1] = qb1 + b21; }
                if (rowb + 2 < n) { logits[(size_t)(rowb + 2) * 2 + 0] = qa2 + b20;
                                    logits[(size_t)(rowb + 2) * 2 + 1] = qb2 + b21; }
                if (rowb + 3 < n) { logits[(size_t)(rowb + 3) * 2 + 0] = qa3 + b20;
                                    logits[(size_t)(rowb + 3) * 2 + 1] = qb3 + b21; }
            }
        }
        base = nbase; d = nd;
    }
}

// Merged: blocks [0,gbw) run the wallet job (never HEAD), rest run the tx job.
template<bool HEAD>
__global__ __launch_bounds__(256)
void sageg2_kernel(const bf16* __restrict__ hw, const int* __restrict__ rpw,
                   const int* __restrict__ dgw, const int* __restrict__ clw,
                   const bf16* __restrict__ xw,
                   const float* __restrict__ Wlw, const float* __restrict__ blw,
                   const float* __restrict__ Wrw,
                   float* __restrict__ outfw, bf16* __restrict__ outbw, int nw, int gbw,
                   const bf16* __restrict__ ht, const int* __restrict__ rpt,
                   const int* __restrict__ dgt, const int* __restrict__ clt,
                   const bf16* __restrict__ xt,
                   const float* __restrict__ Wlt, const float* __restrict__ blt,
                   const float* __restrict__ Wrt,
                   float* __restrict__ outft, bf16* __restrict__ outbt,
                   const float* __restrict__ Wh1, const float* __restrict__ bh1,
                   const float* __restrict__ Wh2, const float* __restrict__ bh2,
                   float* __restrict__ logits, int nt) {
    __shared__ __align__(16) short sW[(HEAD ? 24 : 16) * 64 * 8];   // 16/24 KB
    __shared__ __align__(16) short sH[HEAD ? 64 * 64 : 8];          //  8 KB (HEAD)
    if ((int)blockIdx.x < gbw)
        sageg_body<false>(hw, rpw, dgw, clw, xw, Wlw, blw, Wrw, outfw, outbw,
                          nullptr, nullptr, nullptr, nullptr, nullptr, nw, blockIdx.x, sW, sH);
    else
        sageg_body<HEAD>(ht, rpt, dgt, clt, xt, Wlt, blt, Wrt, outft, outbt,
                         Wh1, bh1, Wh2, bh2, logits, nt, blockIdx.x - gbw, sW, sH);
}

extern "C" void kernel_launch(void* const* d_in, const int* in_sizes, int n_in,
                              void* d_out, int out_size, void* d_ws, size_t ws_size,
                              hipStream_t stream) {
    const float* x_tx   = (const float*)d_in[0];
    const float* x_w    = (const float*)d_in[1];
    const int*   src_tw = (const int*)d_in[2];
    const int*   dst_tw = (const int*)d_in[3];
    const int*   src_wt = (const int*)d_in[4];
    const int*   dst_wt = (const int*)d_in[5];
    const float* Win_tx = (const float*)d_in[6];
    const float* bin_tx = (const float*)d_in[7];
    const float* Win_w  = (const float*)d_in[8];
    const float* bin_w  = (const float*)d_in[9];
    const float* Wl1_tw = (const float*)d_in[10];
    const float* bl1_tw = (const float*)d_in[11];
    const float* Wr1_tw = (const float*)d_in[12];
    const float* Wl1_wt = (const float*)d_in[13];
    const float* bl1_wt = (const float*)d_in[14];
    const float* Wr1_wt = (const float*)d_in[15];
    const float* Wl2_tw = (const float*)d_in[16];
    const float* bl2_tw = (const float*)d_in[17];
    const float* Wr2_tw = (const float*)d_in[18];
    const float* Wl2_wt = (const float*)d_in[19];
    const float* bl2_wt = (const float*)d_in[20];
    const float* Wr2_wt = (const float*)d_in[21];
    const float* Wh1    = (const float*)d_in[22];
    const float* bh1    = (const float*)d_in[23];
    const float* Wh2    = (const float*)d_in[24];
    const float* bh2    = (const float*)d_in[25];

    const int n_tx  = in_sizes[0] / 64;
    const int n_w   = in_sizes[1] / 32;
    const int ne_tw = in_sizes[2];
    const int ne_wt = in_sizes[4];

    // ---- workspace layout (~367 MB); A2/B2 are the conv ping-pong targets ----
    bf16* A2      = (bf16*)d_ws;                          // n_tx*64 bf16: t1
    bf16* B2      = A2 + (size_t)n_tx * 64;               // n_w *64 bf16: w1
    bf16* A       = B2 + (size_t)n_w * 64;                // n_tx*64 bf16: h_tx
    bf16* B       = A + (size_t)n_tx * 64;                // n_w *64 bf16: h_w
    int*  deg_w   = (int*)(B + (size_t)n_w * 64);         // n_w
    int*  deg_tx  = deg_w + n_w;                          // n_tx
    int*  rp_w    = deg_tx + n_tx;                        // n_w
    int*  rp_tx   = rp_w + n_w;                           // n_tx
    int*  ex_w    = rp_tx + n_tx;                         // n_w  (scan scratch)
    int*  ex_tx   = ex_w + n_w;                           // n_tx
    int*  col_tw  = ex_tx + n_tx;                         // ne_tw
    int*  col_wt  = col_tw + ne_tw;                       // ne_wt
    int*  rank_tw = col_wt + ne_wt;                       // ne_tw
    int*  rank_wt = rank_tw + ne_tw;                      // ne_wt
    int*  part_w  = rank_wt + ne_wt;                      // <=4096
    int*  part_tx = part_w + 4096;                        // <=4096

    float* out_logits = (float*)d_out;
    float* out_t2 = out_logits + (size_t)n_tx * 2;
    float* out_w2 = out_t2 + (size_t)n_tx * 64;

    dim3 blk(256);
    int gp64 = (n_tx + 511) / 512;
    int gp32 = (n_w + 63) / 64;
    int gs_w  = (n_w + 511) / 512;
    int gs_tx = (n_tx + 511) / 512;
    int gsc = (ne_tw + ne_wt + 255) / 256;
    int gcr = (ne_tw + ne_wt + 511) / 512;   // count_rank: 2 edges/thread
    int np_w  = (n_w + 1023) / 1024;
    int np_tx = (n_tx + 1023) / 1024;
    int nbw = (n_w + 255) / 256;
    int nbt = (n_tx + 255) / 256;

    // ---- CSR build: count+rank, scans (graph static, reused by both convs) ----
    hipMemsetAsync(deg_w, 0, (size_t)n_w * sizeof(int), stream);
    hipMemsetAsync(deg_tx, 0, (size_t)n_tx * sizeof(int), stream);
    count_rank2_kernel<<<gcr, blk, 0, stream>>>(dst_tw, deg_w, rank_tw, ne_tw,
                                                dst_wt, deg_tx, rank_wt, ne_wt);
    scan1m_kernel<<<np_w + np_tx, blk, 0, stream>>>(deg_w, ex_w, part_w, n_w, np_w,
                                                    deg_tx, ex_tx, part_tx, n_tx);
    scan2m_kernel<<<2, blk, 0, stream>>>(part_w, np_w, part_tx, np_tx);
    scan3m_kernel<<<nbw + nbt, blk, 0, stream>>>(ex_w, part_w, rp_w, n_w, nbw,
                                                 ex_tx, part_tx, rp_tx, n_tx);

    // ---- fused front: rank-scatter (no atomics) + proj64 + proj32, one launch ----
    fused_front_kernel<<<gsc + gp64 + gp32, blk, 0, stream>>>(
        src_tw, dst_tw, rank_tw, rp_w, col_tw, ne_tw,
        src_wt, dst_wt, rank_wt, rp_tx, col_wt, ne_wt, gsc,
        x_tx, Win_tx, bin_tx, A, n_tx, gp64,
        x_w, Win_w, bin_w, B, n_w);

    // ---- conv1 (fused gather+GEMM; reads A,B only, writes A2,B2) ----
    sageg2_kernel<false><<<gs_w + gs_tx, blk, 0, stream>>>(
        A, rp_w, deg_w, col_tw, B, Wl1_tw, bl1_tw, Wr1_tw, nullptr, B2, n_w, gs_w,
        B, rp_tx, deg_tx, col_wt, A, Wl1_wt, bl1_wt, Wr1_wt, nullptr, A2,
        nullptr, nullptr, nullptr, nullptr, nullptr, n_tx);

    // ---- conv2 (fused; reads A2,B2, writes f32 outputs; tx has HEAD) ----
    sageg2_kernel<true><<<gs_w + gs_tx, blk, 0, stream>>>(
        A2, rp_w, deg_w, col_tw, B2, Wl2_tw, bl2_tw, Wr2_tw, out_w2, nullptr, n_w, gs_w,
        B2, rp_tx, deg_tx, col_wt, A2, Wl2_wt, bl2_wt, Wr2_wt, out_t2, nullptr,
        Wh1, bh1, Wh2, bh2, out_logits, n_tx);
}